// Round 12
// baseline (27708.768 us; speedup 1.0000x reference)
//
#include <hip/hip_runtime.h>
#include <cstdint>
#include <cstddef>

#define B_ 64
#define T_ 1024
#define D_ 1024
#define NBLK 256
#define TP_ 256   // probe step count

typedef __attribute__((ext_vector_type(8))) _Float16 half8;
typedef __attribute__((ext_vector_type(4))) float f32x4;
typedef unsigned int u32;
typedef unsigned long long u64;
typedef unsigned short u16;

static __device__ __forceinline__ f32x4 mfma16(half8 a, half8 b, f32x4 c) {
  return __builtin_amdgcn_mfma_f32_16x16x32_f16(a, b, c, 0, 0, 0);
}
static __device__ __forceinline__ u64 cohl64(const u64* p) {
  return __hip_atomic_load(p, __ATOMIC_RELAXED, __HIP_MEMORY_SCOPE_AGENT);
}
static __device__ __forceinline__ u32 cohl32(const u32* p) {
  return __hip_atomic_load(p, __ATOMIC_RELAXED, __HIP_MEMORY_SCOPE_AGENT);
}
static __device__ __forceinline__ void cohs32(u32* p, u32 v) {
  __hip_atomic_store(p, v, __ATOMIC_RELAXED, __HIP_MEMORY_SCOPE_AGENT);
}
static __device__ __forceinline__ u16 h2u(_Float16 h) {
  return __builtin_bit_cast(u16, h);
}

// ---- staging: 32 rows x 1024 fp16 -> regs -> LDS (XOR-swizzled) ----------
static __device__ __forceinline__ void stage_coh(const _Float16* src, u64* st, int tid) {
  const int r = tid >> 5, j = tid & 31;
  const u64* p = (const u64*)(src + (size_t)r * D_) + j * 2;
  #pragma unroll
  for (int k = 0; k < 4; ++k) {
    st[2 * k] = cohl64(p + k * 64);
    st[2 * k + 1] = cohl64(p + k * 64 + 1);
  }
}
static __device__ __forceinline__ void stage_x(const _Float16* src, u64* st, int tid) {
  const int r = tid >> 5, j = tid & 31;
  const u64* p = (const u64*)(src + (size_t)r * T_ * D_) + j * 2;
  #pragma unroll
  for (int k = 0; k < 4; ++k) {
    st[2 * k] = p[k * 64];
    st[2 * k + 1] = p[k * 64 + 1];
  }
}
static __device__ __forceinline__ void stage_xf(const float* src, u64* st, int tid) {
  const int r = tid >> 5, j = tid & 31;
  const float4* p = (const float4*)(src + (size_t)r * T_ * D_) + j * 2;
  #pragma unroll
  for (int k = 0; k < 4; ++k) {
    #pragma unroll
    for (int q = 0; q < 2; ++q) {
      float4 v = p[k * 64 + q];
      union { u16 us[4]; u64 u; } pk;
      pk.us[0] = h2u((_Float16)v.x); pk.us[1] = h2u((_Float16)v.y);
      pk.us[2] = h2u((_Float16)v.z); pk.us[3] = h2u((_Float16)v.w);
      st[2 * k + q] = pk.u;
    }
  }
}
static __device__ __forceinline__ void stage_write(char* lds, const u64* st, int tid) {
  const int r = tid >> 5, j = tid & 31;
  const int sw = (r & 7) << 4;
  char* row = lds + r * 2048;
  #pragma unroll
  for (int k = 0; k < 4; ++k) {
    char* dst = row + ((j * 16 + k * 512) ^ sw);
    *(u64*)dst = st[2 * k];
    *(u64*)(dst + 8) = st[2 * k + 1];
  }
}

// ---- persistent kernel ---------------------------------------------------
// NEW wave layout: 16 waves = mat(2) x kq(4) x colpair(2).
//   mat0 waves: A = bufA (x or h0) vs Wih;  mat1 waves: A = bufB (h_rec) vs Whh
//   -> both GEMMs run CONCURRENTLY; each wave's A-read feeds 4 MFMAs
//      (2 row-tiles x 2 gate-cols) -> LDS read volume HALVED vs r6.
// Partials (mat x kq = 8 per gate elem) land in glpA/glpB which ALIAS the
// (dead-after-gemm) bufA/bufB regions; 128KB dynamic LDS total.
// Barrier: r6 scatter/all-to-all poll (measured-best), bounded spin.
// V: 0=real, 1=NOGEMM, 2=NOBARRIER, 3=NOGLOAD, 4=NOLDSREAD (probes).

template <int V, bool XPRE>
__global__ __launch_bounds__(1024, 4) void lstm_persist(
    const float* __restrict__ x32, const _Float16* __restrict__ xh,
    const _Float16* __restrict__ W,
    _Float16* h0, _Float16* h1,    // [2 parity][B][D] each
    float* __restrict__ out, u32* slots, int ts)
{
  extern __shared__ char lds[];            // 128 KB dynamic
  char* bufA = lds;
  char* bufB = lds + 65536;
  float (*glpA)[32][68] = (float (*)[32][68])lds;
  float (*glpB)[32][68] = (float (*)[32][68])(lds + 65536);

  const int tid = threadIdx.x;
  const int lane = tid & 63;
  const int wv = tid >> 6;
  const int mat = wv & 1;
  const int kq = (wv >> 1) & 3;
  const int cp = wv >> 3;                  // gate pair {0,1} or {2,3}
  const int r = lane & 15;
  const int klane = lane >> 4;
  const int kl2 = klane << 4;
  const int bid = blockIdx.x;
  const int slot = bid >> 3;
  const int lyr = slot >> 4;
  const int mh = (slot >> 3) & 1;
  const int dgrp = (bid & 7) * 8 + (slot & 7);
  const int d0 = dgrp << 4;
  const int mbase = mh << 5;

  // ---- B preload: 16 half8 (64 VGPR) for THIS wave's matrix ----
  const _Float16* Wbase = W + (size_t)(2 * lyr + mat) * 4096 * 1024;
  half8 wB[2][8];
  #pragma unroll
  for (int ct = 0; ct < 2; ++ct) {
    const _Float16* wr = Wbase + (size_t)((cp * 2 + ct) * 1024 + d0 + r) * 1024
                         + kq * 256 + klane * 8;
    #pragma unroll
    for (int ks = 0; ks < 8; ++ks)
      wB[ct][ks] = *(const half8*)(wr + ks * 32);
  }
  #pragma unroll
  for (int ct = 0; ct < 2; ++ct)
    #pragma unroll
    for (int ks = 0; ks < 8; ++ks)
      asm volatile("" : "+v"(wB[ct][ks]));

  float creg0 = 0.f, creg1 = 0.f;
  const int cb = tid >> 3;
  const int cd = (tid & 7) << 1;
  const size_t HS = (size_t)B_ * D_;

  u64 st[8];
  #pragma unroll
  for (int j = 0; j < 8; ++j) st[j] = 0;
  if (V != 3 && lyr == 0) {
    if (XPRE) stage_x(xh + (size_t)mbase * T_ * D_, st, tid);
    else      stage_xf(x32 + (size_t)mbase * T_ * D_, st, tid);
  }

  for (int s = 0; s <= ts; ++s) {
    const bool active = lyr ? (s >= 1) : (s < ts);
    const int t = lyr ? (s - 1) : s;
    const int pp = (s + 1) & 1, cc = s & 1;

    if (active) {
      const _Float16* h0prev = h0 + (size_t)pp * HS + (size_t)mbase * D_;
      if (lyr == 0) {
        stage_write(bufA, st, tid);                // x[t] from prefetch regs
        if (V != 3) stage_coh(h0prev, st, tid);    // h0 recurrent
        stage_write(bufB, st, tid);
      } else {
        if (V != 3) stage_coh(h0prev, st, tid);    // h0[t] (Wih operand)
        stage_write(bufA, st, tid);
        if (V != 3)
          stage_coh(h1 + (size_t)cc * HS + (size_t)mbase * D_, st, tid);
        stage_write(bufB, st, tid);
      }
      __syncthreads();                             // bufs ready

      f32x4 a00 = {0.f,0.f,0.f,0.f}, a10 = {0.f,0.f,0.f,0.f};
      f32x4 a01 = {0.f,0.f,0.f,0.f}, a11 = {0.f,0.f,0.f,0.f};
      if constexpr (V == 1) {
        // NOGEMM: keep staged LDS observable (prevent ds_write DCE)
        u32 d1 = *(const u32*)(bufA + tid * 16);
        u32 d2 = *(const u32*)(bufB + tid * 16);
        asm volatile("" :: "v"(d1), "v"(d2));
      } else {
        const char* buf = mat ? bufB : bufA;
        const int sw = (r & 7) << 4;
        const char* p0 = buf + r * 2048;
        const char* p1 = buf + (16 + r) * 2048;
        if constexpr (V == 4) {
          u32 d1 = *(const u32*)(bufA + tid * 16);
          u32 d2 = *(const u32*)(bufB + tid * 16);
          asm volatile("" :: "v"(d1), "v"(d2));
        }
        #pragma unroll
        for (int ks = 0; ks < 8; ++ks) {
          const int kb = (kq * 512 + ks * 64 + kl2) ^ sw;
          half8 a0, a1;
          if constexpr (V == 4) { a0 = wB[0][ks]; a1 = wB[1][ks]; }
          else {
            a0 = *(const half8*)(p0 + kb);
            a1 = *(const half8*)(p1 + kb);
          }
          a00 = mfma16(a0, wB[0][ks], a00);        // mt0, gate cp*2
          a10 = mfma16(a1, wB[0][ks], a10);        // mt1, gate cp*2
          a01 = mfma16(a0, wB[1][ks], a01);        // mt0, gate cp*2+1
          a11 = mfma16(a1, wB[1][ks], a11);        // mt1, gate cp*2+1
        }
      }
      __syncthreads();                             // all gemm reads done

      {                                            // partials -> glp (alias bufs)
        float (*glpX)[32][68] = mat ? glpB : glpA;
        const int r4 = klane << 2;
        const int c0 = (cp * 2) * 16 + r;
        const int c1 = (cp * 2 + 1) * 16 + r;
        #pragma unroll
        for (int i = 0; i < 4; ++i) {
          glpX[kq][r4 + i][c0]      = a00[i];
          glpX[kq][16 + r4 + i][c0] = a10[i];
          glpX[kq][r4 + i][c1]      = a01[i];
          glpX[kq][16 + r4 + i][c1] = a11[i];
        }
      }
      __syncthreads();                             // glp ready

      if (tid < 256) {
        float g4[4][2];
        #pragma unroll
        for (int gg = 0; gg < 4; ++gg) {
          float s0 = 0.f, s1 = 0.f;
          #pragma unroll
          for (int k4 = 0; k4 < 4; ++k4) {
            float2 vA = *(const float2*)&glpA[k4][cb][gg * 16 + cd];
            float2 vB = *(const float2*)&glpB[k4][cb][gg * 16 + cd];
            s0 += vA.x + vB.x;
            s1 += vA.y + vB.y;
          }
          g4[gg][0] = s0; g4[gg][1] = s1;
        }
        const float i0 = 1.f / (1.f + expf(-g4[0][0])), i1 = 1.f / (1.f + expf(-g4[0][1]));
        const float f0 = 1.f / (1.f + expf(-g4[1][0])), f1 = 1.f / (1.f + expf(-g4[1][1]));
        const float z0 = tanhf(g4[2][0]),               z1 = tanhf(g4[2][1]);
        const float o0 = 1.f / (1.f + expf(-g4[3][0])), o1 = 1.f / (1.f + expf(-g4[3][1]));
        creg0 = f0 * creg0 + i0 * z0;
        creg1 = f1 * creg1 + i1 * z1;
        const float hn0 = o0 * tanhf(creg0);
        const float hn1 = o1 * tanhf(creg1);
        union { u16 us[2]; u32 u; } pk;
        pk.us[0] = h2u((_Float16)hn0);
        pk.us[1] = h2u((_Float16)hn1);
        _Float16* hw = lyr ? (h1 + (size_t)pp * HS) : (h0 + (size_t)cc * HS);
        cohs32((u32*)(hw + (size_t)(mbase + cb) * D_ + d0 + cd), pk.u);
        if (lyr) {
          float2 o2; o2.x = hn0; o2.y = hn1;
          *(float2*)(out + ((size_t)(mbase + cb) * T_ + t) * D_ + d0 + cd) = o2;
        }
      }
    }

    // drain sc1 stores (syncthreads emits vmcnt(0)), then r6 barrier
    __syncthreads();
    if constexpr (V != 2) {
      const u32 gen = (u32)(s + 1);
      if (tid == 0) cohs32(slots + bid * 32, gen);
      if (tid < NBLK) {
        const u32* p = slots + tid * 32;
        int spin = 0;
        while (cohl32(p) < gen && ++spin < (1 << 24))
          __builtin_amdgcn_s_sleep(2);
      }
    }
    __syncthreads();

    if (V != 3 && lyr == 0 && s + 1 < ts) {        // prefetch next x
      if (XPRE) stage_x(xh + ((size_t)mbase * T_ + (s + 1)) * D_, st, tid);
      else      stage_xf(x32 + ((size_t)mbase * T_ + (s + 1)) * D_, st, tid);
    }
  }
}

// ---- setup ---------------------------------------------------------------

__global__ void convw(const float* __restrict__ w0, const float* __restrict__ w1,
                      const float* __restrict__ w2, const float* __restrict__ w3,
                      u64* __restrict__ dst) {
  const size_t n1 = (size_t)D_ * D_;
  const size_t n = 4 * n1;
  for (size_t i = (size_t)blockIdx.x * blockDim.x + threadIdx.x; i < n;
       i += (size_t)gridDim.x * blockDim.x) {
    const size_t m = i / n1, j = i - m * n1;
    const float* src = (m == 0) ? w0 : (m == 1) ? w1 : (m == 2) ? w2 : w3;
    float4 v = ((const float4*)src)[j];
    union { u16 us[4]; u64 u; } pk;
    pk.us[0] = h2u((_Float16)v.x); pk.us[1] = h2u((_Float16)v.y);
    pk.us[2] = h2u((_Float16)v.z); pk.us[3] = h2u((_Float16)v.w);
    dst[i] = pk.u;
  }
}

__global__ void convx(const float* __restrict__ x, u64* __restrict__ xh) {
  const size_t n = (size_t)B_ * T_ * D_ / 4;
  for (size_t i = (size_t)blockIdx.x * blockDim.x + threadIdx.x; i < n;
       i += (size_t)gridDim.x * blockDim.x) {
    float4 v = ((const float4*)x)[i];
    union { u16 us[4]; u64 u; } pk;
    pk.us[0] = h2u((_Float16)v.x); pk.us[1] = h2u((_Float16)v.y);
    pk.us[2] = h2u((_Float16)v.z); pk.us[3] = h2u((_Float16)v.w);
    xh[i] = pk.u;
  }
}

// ---- host ----------------------------------------------------------------

extern "C" void kernel_launch(void* const* d_in, const int* in_sizes, int n_in,
                              void* d_out, int out_size, void* d_ws, size_t ws_size,
                              hipStream_t stream) {
  (void)in_sizes; (void)n_in; (void)out_size;
  const float* x = (const float*)d_in[0];
  const float* Wih0 = (const float*)d_in[1];
  const float* Whh0 = (const float*)d_in[2];
  const float* Wih1 = (const float*)d_in[3];
  const float* Whh1 = (const float*)d_in[4];
  float* out = (float*)d_out;

  char* ws = (char*)d_ws;
  const size_t MB = 1ull << 20;
  const size_t KB = 1024;
  // layout: [0,32MB) W fp16
  //   32MB: h0 real 256KB | h1 real 256KB | slots 5x32KB | (pad)
  //   33MB: probe h scratch (hp0 256KB, hp1 256KB)
  //   34MB: xh 128MB
  _Float16* Wf = (_Float16*)ws;
  _Float16* h0 = (_Float16*)(ws + 32 * MB);
  _Float16* h1 = (_Float16*)(ws + 32 * MB + 256 * KB);
  u32* slots = (u32*)(ws + 32 * MB + 512 * KB);    // 5 sets x 8192 u32
  _Float16* hp0 = (_Float16*)(ws + 33 * MB);
  _Float16* hp1 = (_Float16*)(ws + 33 * MB + 256 * KB);
  _Float16* xh = (_Float16*)(ws + 34 * MB);
  const bool xpre = ws_size >= 34 * MB + (size_t)B_ * T_ * D_ * 2;

  hipMemsetAsync(ws + 32 * MB, 0, 672 * KB, stream);   // h0,h1 + all slot sets
  convw<<<4096, 256, 0, stream>>>(Wih0, Whh0, Wih1, Whh1, (u64*)Wf);

  if (xpre) {
    convx<<<4096, 256, 0, stream>>>(x, (u64*)xh);
    // ---- ablation probes (TP_=256 steps, scratch buffers) ----
    lstm_persist<1, true><<<NBLK, 1024, 131072, stream>>>(x, xh, Wf, hp0, hp1, out, slots + 1 * 8192, TP_);
    lstm_persist<2, true><<<NBLK, 1024, 131072, stream>>>(x, xh, Wf, hp0, hp1, out, slots + 2 * 8192, TP_);
    lstm_persist<3, true><<<NBLK, 1024, 131072, stream>>>(x, xh, Wf, hp0, hp1, out, slots + 3 * 8192, TP_);
    lstm_persist<4, true><<<NBLK, 1024, 131072, stream>>>(x, xh, Wf, hp0, hp1, out, slots + 4 * 8192, TP_);
    // ---- real kernel (overwrites every out element) ----
    lstm_persist<0, true><<<NBLK, 1024, 131072, stream>>>(x, xh, Wf, h0, h1, out, slots, T_);
  } else {
    lstm_persist<1, false><<<NBLK, 1024, 131072, stream>>>(x, xh, Wf, hp0, hp1, out, slots + 1 * 8192, TP_);
    lstm_persist<2, false><<<NBLK, 1024, 131072, stream>>>(x, xh, Wf, hp0, hp1, out, slots + 2 * 8192, TP_);
    lstm_persist<3, false><<<NBLK, 1024, 131072, stream>>>(x, xh, Wf, hp0, hp1, out, slots + 3 * 8192, TP_);
    lstm_persist<4, false><<<NBLK, 1024, 131072, stream>>>(x, xh, Wf, hp0, hp1, out, slots + 4 * 8192, TP_);
    lstm_persist<0, false><<<NBLK, 1024, 131072, stream>>>(x, xh, Wf, h0, h1, out, slots, T_);
  }
}

// Round 13
// 8491.746 us; speedup vs baseline: 3.2630x; 3.2630x over previous
//
#include <hip/hip_runtime.h>
#include <cstdint>
#include <cstddef>

#define B_ 64
#define T_ 1024
#define D_ 1024
#define NBLK 256

typedef __attribute__((ext_vector_type(8))) _Float16 half8;
typedef __attribute__((ext_vector_type(4))) float f32x4;
typedef unsigned int u32;
typedef unsigned long long u64;
typedef unsigned short u16;

static __device__ __forceinline__ f32x4 mfma16(half8 a, half8 b, f32x4 c) {
  return __builtin_amdgcn_mfma_f32_16x16x32_f16(a, b, c, 0, 0, 0);
}
static __device__ __forceinline__ u64 cohl64(const u64* p) {
  return __hip_atomic_load(p, __ATOMIC_RELAXED, __HIP_MEMORY_SCOPE_AGENT);
}
static __device__ __forceinline__ u32 cohl32(const u32* p) {
  return __hip_atomic_load(p, __ATOMIC_RELAXED, __HIP_MEMORY_SCOPE_AGENT);
}
static __device__ __forceinline__ void cohs32(u32* p, u32 v) {
  __hip_atomic_store(p, v, __ATOMIC_RELAXED, __HIP_MEMORY_SCOPE_AGENT);
}
static __device__ __forceinline__ u16 h2u(_Float16 h) {
  return __builtin_bit_cast(u16, h);
}

// ---- staging: 32 rows x 1024 fp16 -> regs -> LDS (XOR-swizzled) ----------
// thread t: row r=t>>5, lane j=t&31; covers bytes j*16 + k*512 (k=0..3).

static __device__ __forceinline__ void stage_coh(const _Float16* src, u64* st, int tid) {
  const int r = tid >> 5, j = tid & 31;
  const u64* p = (const u64*)(src + (size_t)r * D_) + j * 2;
  #pragma unroll
  for (int k = 0; k < 4; ++k) {
    st[2 * k] = cohl64(p + k * 64);
    st[2 * k + 1] = cohl64(p + k * 64 + 1);
  }
}

static __device__ __forceinline__ void stage_x(const _Float16* src, u64* st, int tid) {
  const int r = tid >> 5, j = tid & 31;
  const u64* p = (const u64*)(src + (size_t)r * T_ * D_) + j * 2;
  #pragma unroll
  for (int k = 0; k < 4; ++k) {
    st[2 * k] = p[k * 64];
    st[2 * k + 1] = p[k * 64 + 1];
  }
}

static __device__ __forceinline__ void stage_xf(const float* src, u64* st, int tid) {
  const int r = tid >> 5, j = tid & 31;
  const float4* p = (const float4*)(src + (size_t)r * T_ * D_) + j * 2;
  #pragma unroll
  for (int k = 0; k < 4; ++k) {
    #pragma unroll
    for (int q = 0; q < 2; ++q) {
      float4 v = p[k * 64 + q];
      union { u16 us[4]; u64 u; } pk;
      pk.us[0] = h2u((_Float16)v.x); pk.us[1] = h2u((_Float16)v.y);
      pk.us[2] = h2u((_Float16)v.z); pk.us[3] = h2u((_Float16)v.w);
      st[2 * k + q] = pk.u;
    }
  }
}

static __device__ __forceinline__ void stage_write(char* lds, const u64* st, int tid) {
  const int r = tid >> 5, j = tid & 31;
  const int sw = (r & 7) << 4;
  char* row = lds + r * 2048;
  #pragma unroll
  for (int k = 0; k < 4; ++k) {
    char* dst = row + ((j * 16 + k * 512) ^ sw);
    *(u64*)dst = st[2 * k];
    *(u64*)(dst + 8) = st[2 * k + 1];
  }
}

// ---- GEMM: weights preloaded to regs (pinned; compiler may remat from L2) -
static __device__ __forceinline__ void gemm_reg(
    f32x4* acc, const char* ldsA, const half8* w, int kq, int lane) {
  const int r = lane & 15;
  const int kl2 = (lane >> 4) << 4;
  const int sw = (r & 7) << 4;
  const char* p0 = ldsA + r * 2048;
  const char* p1 = ldsA + (16 + r) * 2048;   // (16+r)&7 == r&7 -> same swizzle
  #pragma unroll
  for (int ks = 0; ks < 8; ++ks) {
    const int kb = (kq * 512 + ks * 64 + kl2) ^ sw;
    half8 a0 = *(const half8*)(p0 + kb);
    half8 a1 = *(const half8*)(p1 + kb);
    acc[0] = mfma16(a0, w[ks], acc[0]);
    acc[1] = mfma16(a1, w[ks], acc[1]);
  }
}

// split-group scatter wait: thread i polls slot i. tid<128 = layer-0 group
// (target gen0); tid in [128,256) = layer-1 group (target gen1). Bounded.
static __device__ __forceinline__ void pollwait2(const u32* slots, u32 gen0,
                                                 u32 gen1, int tid) {
  if (tid < NBLK) {
    const u32 tgt = (tid < 128) ? gen0 : gen1;
    if (tgt > 0) {
      const u32* p = slots + tid * 32;
      int spin = 0;
      while (cohl32(p) < tgt && ++spin < (1 << 16))
        __builtin_amdgcn_s_sleep(2);
    }
  }
  __syncthreads();
}

// ---- persistent kernel ---------------------------------------------------
// r6 structure; barrier replaced by DECOUPLED per-layer waits:
//   layer0@s waits: lyr0 group >= s (h0[s-1] ready), lyr1 group >= s-4
//                   (throttle -> bounds skew; h0 rotation depth 8 > skew 5).
//   layer1@s waits: all >= s.
// Layer-0 pipelines ahead of layer-1; each group pays only its own critical
// path instead of the global max. h0: depth-8 rotation (1MB, L3-pinned).
// h1: parity ping-pong (group is self-lockstep; r6 safety argument holds).

template <bool XPRE>
__global__ __launch_bounds__(1024, 4) void lstm_persist(
    const float* __restrict__ x32, const _Float16* __restrict__ xh,
    const _Float16* __restrict__ W,
    _Float16* h0,                  // [8 rot][B][D]
    _Float16* h1,                  // [2 parity][B][D]
    float* __restrict__ out, u32* slots)
{
  __shared__ char ldsA[32 * 2048];
  __shared__ float glp[4][32][68];
  const int tid = threadIdx.x;
  const int lane = tid & 63;
  const int wv = tid >> 6;
  const int kq = wv >> 2;
  const int nt = wv & 3;                   // gate (i,f,g,o)
  const int bid = blockIdx.x;
  const int slot = bid >> 3;
  const int lyr = slot >> 4;               // bid<128 -> lyr0
  const int mh = (slot >> 3) & 1;
  const int dgrp = (bid & 7) * 8 + (slot & 7);
  const int d0 = dgrp << 4;
  const int mbase = mh << 5;

  // ---- weight preload: 8+8 half8 fragments per lane ----
  const _Float16* Wih = W + (size_t)(2 * lyr) * 4096 * 1024;
  const _Float16* Whh = Wih + (size_t)4096 * 1024;
  const size_t wrow = (size_t)(nt * 1024 + d0 + (lane & 15)) * 1024;
  const int kl2 = (lane >> 4) << 4;
  half8 wih[8], whh[8];
  #pragma unroll
  for (int ks = 0; ks < 8; ++ks) {
    const int kb = kq * 512 + ks * 64 + kl2;       // byte offset in row
    wih[ks] = *(const half8*)(Wih + wrow + (kb >> 1));
    whh[ks] = *(const half8*)(Whh + wrow + (kb >> 1));
  }
  #pragma unroll
  for (int ks = 0; ks < 8; ++ks) {
    asm volatile("" : "+v"(wih[ks]));
    asm volatile("" : "+v"(whh[ks]));
  }

  float creg0 = 0.f, creg1 = 0.f;        // cell state in registers
  const int cb = tid >> 3;
  const int cd = (tid & 7) << 1;
  const size_t HS = (size_t)B_ * D_;

  u64 st[8];
  if (lyr == 0) {                        // prefetch x for s=0
    if (XPRE) stage_x(xh + (size_t)mbase * T_ * D_, st, tid);
    else      stage_xf(x32 + (size_t)mbase * T_ * D_, st, tid);
  }

  for (int s = 0; s <= T_; ++s) {
    const bool active = lyr ? (s >= 1) : (s < T_);
    const int t = lyr ? (s - 1) : s;

    // ---- decoupled wait ----
    if (lyr == 0)
      pollwait2(slots, (u32)s, (u32)(s > 4 ? s - 4 : 0), tid);
    else
      pollwait2(slots, (u32)s, (u32)s, tid);

    if (active) {
      // h0 rotation: at step s, layer0 reads h0[(s-1)&7], writes h0[s&7];
      // layer1 reads h0[t&7] = h0[(s-1)&7].
      const _Float16* h0prev = h0 + (size_t)((s + 7) & 7) * HS + (size_t)mbase * D_;
      if (lyr == 0) {
        stage_write(ldsA, st, tid);            // x[t] (prefetched)
        __syncthreads();
        stage_coh(h0prev, st, tid);            // recurrent input (in flight)
      } else {
        stage_coh(h0prev, st, tid);            // h0[t] from layer 0
        stage_write(ldsA, st, tid);
        __syncthreads();
        stage_coh(h1 + (size_t)(s & 1) * HS + (size_t)mbase * D_, st, tid);
      }

      f32x4 acc[2];
      acc[0] = (f32x4){0.f, 0.f, 0.f, 0.f};
      acc[1] = (f32x4){0.f, 0.f, 0.f, 0.f};
      gemm_reg(acc, ldsA, wih, kq, lane);      // GEMM1 (x or h0, vs Wih)
      __syncthreads();
      stage_write(ldsA, st, tid);
      __syncthreads();
      gemm_reg(acc, ldsA, whh, kq, lane);      // GEMM2 (recurrent, vs Whh)

      // kq partials -> LDS
      const int r4 = (lane >> 4) << 2;
      const int ccol = nt * 16 + (lane & 15);
      #pragma unroll
      for (int mt = 0; mt < 2; ++mt)
        #pragma unroll
        for (int i = 0; i < 4; ++i)
          glp[kq][mt * 16 + r4 + i][ccol] = acc[mt][i];
      __syncthreads();

      if (tid < 256) {
        float g4[4][2];
        #pragma unroll
        for (int gg = 0; gg < 4; ++gg) {
          g4[gg][0] = glp[0][cb][gg * 16 + cd] + glp[1][cb][gg * 16 + cd]
                    + glp[2][cb][gg * 16 + cd] + glp[3][cb][gg * 16 + cd];
          g4[gg][1] = glp[0][cb][gg * 16 + cd + 1] + glp[1][cb][gg * 16 + cd + 1]
                    + glp[2][cb][gg * 16 + cd + 1] + glp[3][cb][gg * 16 + cd + 1];
        }
        const float i0 = 1.f / (1.f + expf(-g4[0][0])), i1 = 1.f / (1.f + expf(-g4[0][1]));
        const float f0 = 1.f / (1.f + expf(-g4[1][0])), f1 = 1.f / (1.f + expf(-g4[1][1]));
        const float z0 = tanhf(g4[2][0]),               z1 = tanhf(g4[2][1]);
        const float o0 = 1.f / (1.f + expf(-g4[3][0])), o1 = 1.f / (1.f + expf(-g4[3][1]));
        creg0 = f0 * creg0 + i0 * z0;
        creg1 = f1 * creg1 + i1 * z1;
        const float hn0 = o0 * tanhf(creg0);
        const float hn1 = o1 * tanhf(creg1);
        union { u16 us[2]; u32 u; } pk;
        pk.us[0] = h2u((_Float16)hn0);
        pk.us[1] = h2u((_Float16)hn1);
        _Float16* hw = lyr
            ? (h1 + (size_t)((s + 1) & 1) * HS)      // h1[t&1] == (s-1)&1
            : (h0 + (size_t)(s & 7) * HS);           // h0[s&7]
        cohs32((u32*)(hw + (size_t)(mbase + cb) * D_ + d0 + cd), pk.u);
        if (lyr) {
          float2 o2; o2.x = hn0; o2.y = hn1;
          *(float2*)(out + ((size_t)(mbase + cb) * T_ + t) * D_ + d0 + cd) = o2;
        }
      }
    }

    // drain sc1 stores (syncthreads emits vmcnt(0)), then arrive gen s+1
    __syncthreads();
    if (tid == 0) cohs32(slots + bid * 32, (u32)(s + 1));

    // prefetch next x after arrive (never delays the signal)
    if (lyr == 0 && s + 1 < T_) {
      if (XPRE) stage_x(xh + ((size_t)mbase * T_ + (s + 1)) * D_, st, tid);
      else      stage_xf(x32 + ((size_t)mbase * T_ + (s + 1)) * D_, st, tid);
    }
  }
}

// ---- setup ---------------------------------------------------------------

__global__ void convw(const float* __restrict__ w0, const float* __restrict__ w1,
                      const float* __restrict__ w2, const float* __restrict__ w3,
                      u64* __restrict__ dst) {
  const size_t n1 = (size_t)D_ * D_;          // float4 count per matrix
  const size_t n = 4 * n1;
  for (size_t i = (size_t)blockIdx.x * blockDim.x + threadIdx.x; i < n;
       i += (size_t)gridDim.x * blockDim.x) {
    const size_t m = i / n1, j = i - m * n1;
    const float* src = (m == 0) ? w0 : (m == 1) ? w1 : (m == 2) ? w2 : w3;
    float4 v = ((const float4*)src)[j];
    union { u16 us[4]; u64 u; } pk;
    pk.us[0] = h2u((_Float16)v.x); pk.us[1] = h2u((_Float16)v.y);
    pk.us[2] = h2u((_Float16)v.z); pk.us[3] = h2u((_Float16)v.w);
    dst[i] = pk.u;
  }
}

__global__ void convx(const float* __restrict__ x, u64* __restrict__ xh) {
  const size_t n = (size_t)B_ * T_ * D_ / 4;
  for (size_t i = (size_t)blockIdx.x * blockDim.x + threadIdx.x; i < n;
       i += (size_t)gridDim.x * blockDim.x) {
    float4 v = ((const float4*)x)[i];
    union { u16 us[4]; u64 u; } pk;
    pk.us[0] = h2u((_Float16)v.x); pk.us[1] = h2u((_Float16)v.y);
    pk.us[2] = h2u((_Float16)v.z); pk.us[3] = h2u((_Float16)v.w);
    xh[i] = pk.u;
  }
}

// ---- host ----------------------------------------------------------------

extern "C" void kernel_launch(void* const* d_in, const int* in_sizes, int n_in,
                              void* d_out, int out_size, void* d_ws, size_t ws_size,
                              hipStream_t stream) {
  (void)in_sizes; (void)n_in; (void)out_size;
  const float* x = (const float*)d_in[0];
  const float* Wih0 = (const float*)d_in[1];
  const float* Whh0 = (const float*)d_in[2];
  const float* Wih1 = (const float*)d_in[3];
  const float* Whh1 = (const float*)d_in[4];
  float* out = (float*)d_out;

  char* ws = (char*)d_ws;
  const size_t MB = 1ull << 20;
  const size_t KB = 1024;
  // layout: [0,32MB) W fp16
  //   32MB: h0 rot8 1MB | 33MB: h1 par2 256KB | slots 32KB | 34MB: xh 128MB
  _Float16* Wf = (_Float16*)ws;
  _Float16* h0 = (_Float16*)(ws + 32 * MB);
  _Float16* h1 = (_Float16*)(ws + 33 * MB);
  u32* slots = (u32*)(ws + 33 * MB + 256 * KB);
  _Float16* xh = (_Float16*)(ws + 34 * MB);
  const bool xpre = ws_size >= 34 * MB + (size_t)B_ * T_ * D_ * 2;

  hipMemsetAsync(ws + 32 * MB, 0, 1 * MB + 256 * KB + 32 * KB, stream);
  convw<<<4096, 256, 0, stream>>>(Wih0, Whh0, Wih1, Whh1, (u64*)Wf);
  if (xpre) {
    convx<<<4096, 256, 0, stream>>>(x, (u64*)xh);
    lstm_persist<true><<<NBLK, 1024, 0, stream>>>(x, xh, Wf, h0, h1, out, slots);
  } else {
    lstm_persist<false><<<NBLK, 1024, 0, stream>>>(x, xh, Wf, h0, h1, out, slots);
  }
}